// Round 7
// baseline (361.338 us; speedup 1.0000x reference)
//
#include <hip/hip_runtime.h>

#define BATCH 8192
#define DIM 64
#define INV_TEMP 14.2857142857142857f  // 1/0.07
#define EPS_NORM 1e-8f
#define NXB 32          // column blocks (256 cols each) -> grid.x

typedef __attribute__((ext_vector_type(8))) short bf16x8;
typedef __attribute__((ext_vector_type(4))) float f32x4;

__device__ __forceinline__ unsigned short f2bf_rne(float x) {
  unsigned int u = __float_as_uint(x);
  u += 0x7FFFu + ((u >> 16) & 1u);   // round-to-nearest-even
  return (unsigned short)(u >> 16);
}

// ---------------------------------------------------------------------------
// Kernel 1: per-row norms (one wave per row for A and B), write normalized
// bf16 copies. Also zero-init out[0] for the loss atomics.
// ---------------------------------------------------------------------------
__global__ __launch_bounds__(256) void norm_kernel(
    const float* __restrict__ A, const float* __restrict__ Bm,
    unsigned short* __restrict__ An, unsigned short* __restrict__ Bn,
    float* __restrict__ out) {
  int gid  = blockIdx.x * 256 + threadIdx.x;
  int row  = gid >> 6;
  int lane = gid & 63;
  float a = A[row * DIM + lane];
  float b = Bm[row * DIM + lane];
  float sa = a * a, sb = b * b;
#pragma unroll
  for (int m = 32; m; m >>= 1) {   // butterfly: all lanes end with the sum
    sa += __shfl_xor(sa, m);
    sb += __shfl_xor(sb, m);
  }
  float ia = 1.0f / fmaxf(sqrtf(sa), EPS_NORM);
  float ib = 1.0f / fmaxf(sqrtf(sb), EPS_NORM);
  An[row * DIM + lane] = f2bf_rne(a * ia);
  Bn[row * DIM + lane] = f2bf_rne(b * ib);
  if (gid == 0) out[0] = 0.0f;
}

// ---------------------------------------------------------------------------
// Kernel 2: MFMA cos + LDS transpose-stage + fill-shaped row stores.
//
//   Evidence (rounds 0/5/6): every MFMA-fragment-shaped store variant pins at
//   ~2.0 TB/s raw write BW (16x 64B segments @32KB stride, +4B misaligned per
//   instruction), while the harness fill kernel hits 5.7 TB/s with 1KB
//   contiguous aligned stores. Fix the ADDRESS PATTERN, not the instruction.
//
//   Structure: 128 threads = 2 waves; wave w owns rows [by*32+16w .. +16) x
//   cols [bx*256 .. +256). 16 col-tiles of swapped-operand MFMA
//   (lane(m,q) reg r = S[row0+m][16nt+4q+r]) staged to LDS with slot = col+1
//   (mod 256), row stride 264 floats (16B-aligned rows, bounded bank spread).
//   Flush: one ROW per wave instruction - lane l reads LDS floats [4l..4l+3]
//   of row j and stores memory floats row*8192 + bcol0 + 4l (16B ALIGNED,
//   1KB contiguous per instruction == fill pattern), which holds output cols
//   [bcol0+4l-1 .. +2] thanks to the slot shift (out+1 misalignment absorbed).
//
//   Ownership (every byte exactly one writer, replay-idempotent):
//     lane 0:    nt dwords at +1,+2,+3 (cols 0..2) and +256 (col 255)
//     lanes 1-7: nt dwordx4  (+4 .. +31; boundary line region)
//     lanes 8-63: cached dwordx4 (+32 .. +255; full single-writer lines)
//   Boundary line [256bx .. +31] writers: left block's +256 tail (nt) +
//   our lanes 0-7 (nt) -> all-nt, never cached-dirty in two L2s (round-3 fix).
//   exp / label-masked row sums ride the flush read-back (64-lane butterfly);
//   no __syncthreads anywhere (waves fully independent).
// ---------------------------------------------------------------------------
__global__ __launch_bounds__(128) void cos_mfma_kernel(
    const unsigned short* __restrict__ An, const unsigned short* __restrict__ Bn,
    const int* __restrict__ labels,
    float* __restrict__ pN, float* __restrict__ pD,
    float* __restrict__ out /* d_out base; cos matrix lives at out+1 */) {
  const int tid = threadIdx.x;
  const int l = tid & 63;
  const int w = tid >> 6;          // 0..1
  const int m = l & 15, q = l >> 4;
  const int bcol0 = blockIdx.x * 256;
  const int R0 = blockIdx.y * 32 + w * 16;   // wave's first row

  __shared__ float lds[2][16][264];          // 33.8 KB

  // ---- A fragments for this wave's 16 rows (K=64 -> 2 x bf16x8)
  bf16x8 afr[2];
#pragma unroll
  for (int h = 0; h < 2; ++h)
    afr[h] = *(const bf16x8*)(An + (size_t)(R0 + m) * DIM + h * 32 + q * 8);

  // row labels (lane m holds row R0+m's label); col labels for flush lanes
  int lr = labels[R0 + m];
  int labc[4];
#pragma unroll
  for (int r = 0; r < 4; ++r)
    labc[r] = labels[bcol0 + ((4 * l + r - 1) & 255)];

  // ---- stage: 16 col-tiles -> LDS (slot = col+1 mod 256)
#pragma unroll
  for (int nt = 0; nt < 16; ++nt) {
    const unsigned short* bp = Bn + (size_t)(bcol0 + nt * 16 + m) * DIM + q * 8;
    bf16x8 b0 = *(const bf16x8*)(bp);
    bf16x8 b1 = *(const bf16x8*)(bp + 32);
    f32x4 a = {0.f, 0.f, 0.f, 0.f};
    a = __builtin_amdgcn_mfma_f32_16x16x32_bf16(b0, afr[0], a, 0, 0, 0);
    a = __builtin_amdgcn_mfma_f32_16x16x32_bf16(b1, afr[1], a, 0, 0, 0);
#pragma unroll
    for (int r = 0; r < 4; ++r)
      lds[w][m][(nt * 16 + q * 4 + r + 1) & 255] = a[r];
  }

  // ---- flush: one row per instruction (1KB contiguous, aligned)
  float esk = 0.f, nsk = 0.f;
#pragma unroll
  for (int j = 0; j < 16; ++j) {
    f32x4 v = *(const f32x4*)&lds[w][j][4 * l];   // cols {4l-1..4l+2}; lane0: {255,0,1,2}
    size_t base = (size_t)(R0 + j) * BATCH + bcol0;
    float* p = out + base + 4 * l;
    if (l == 0) {
      __builtin_nontemporal_store(v[1], out + base + 1);
      __builtin_nontemporal_store(v[2], out + base + 2);
      __builtin_nontemporal_store(v[3], out + base + 3);
      __builtin_nontemporal_store(v[0], out + base + 256);
    } else if (l < 8) {
      __builtin_nontemporal_store(v, (f32x4*)p);
    } else {
      *(f32x4*)p = v;
    }
    // fused exp + label-masked row sum (row j), full-wave butterfly
    float e0 = __expf(v[0] * INV_TEMP);
    float e1 = __expf(v[1] * INV_TEMP);
    float e2 = __expf(v[2] * INV_TEMP);
    float e3 = __expf(v[3] * INV_TEMP);
    float es = (e0 + e1) + (e2 + e3);
    int lrj = __shfl(lr, j);
    float ns = 0.f;
    if (labc[0] == lrj) ns += e0;
    if (labc[1] == lrj) ns += e1;
    if (labc[2] == lrj) ns += e2;
    if (labc[3] == lrj) ns += e3;
#pragma unroll
    for (int msk = 1; msk < 64; msk <<= 1) {
      es += __shfl_xor(es, msk);
      ns += __shfl_xor(ns, msk);
    }
    if ((l & 15) == j) { esk = es; nsk = ns; }
  }

  if (l < 16) {
    pN[(size_t)blockIdx.x * BATCH + R0 + l] = nsk;
    pD[(size_t)blockIdx.x * BATCH + R0 + l] = esk;
  }
}

// ---------------------------------------------------------------------------
// Kernel 3: reduce the NXB partials per row, loss = -mean(log(n'/d)).
// 32 blocks x 256 threads = 8192 rows; one atomicAdd per block into out[0]
// (zero-initialized by norm_kernel).
// ---------------------------------------------------------------------------
__global__ __launch_bounds__(256) void loss_kernel(
    const float* __restrict__ pN, const float* __restrict__ pD,
    float* __restrict__ out) {
  int r = blockIdx.x * 256 + threadIdx.x;
  float n = 0.f, d = 0.f;
#pragma unroll
  for (int j = 0; j < NXB; ++j) {
    n += pN[(size_t)j * BATCH + r];
    d += pD[(size_t)j * BATCH + r];
  }
  n = (n == 0.0f) ? (n + 0.01f) : n;
  float s = logf(n / d);
#pragma unroll
  for (int m = 32; m; m >>= 1) s += __shfl_xor(s, m);
  __shared__ float red[4];
  if ((threadIdx.x & 63) == 0) red[threadIdx.x >> 6] = s;
  __syncthreads();
  if (threadIdx.x == 0) {
    float t = red[0] + red[1] + red[2] + red[3];
    atomicAdd(out, -t / (float)BATCH);
  }
}

// ---------------------------------------------------------------------------
extern "C" void kernel_launch(void* const* d_in, const int* in_sizes, int n_in,
                              void* d_out, int out_size, void* d_ws, size_t ws_size,
                              hipStream_t stream) {
  const int*   labels = (const int*)d_in[0];
  const float* A      = (const float*)d_in[1];
  const float* Bf     = (const float*)d_in[2];
  float* out = (float*)d_out;  // out[0]=loss, out[1..]=cos_score row-major

  unsigned short* An = (unsigned short*)d_ws;                 // 1 MB
  unsigned short* Bn = An + BATCH * DIM;                      // 1 MB
  float* pN = (float*)(Bn + BATCH * DIM);                     // NXB*32 KB = 1 MB
  float* pD = pN + (size_t)NXB * BATCH;                       // 1 MB

  hipLaunchKernelGGL(norm_kernel, dim3(BATCH * 64 / 256), dim3(256), 0, stream,
                     A, Bf, An, Bn, out);
  hipLaunchKernelGGL(cos_mfma_kernel, dim3(NXB, BATCH / 32), dim3(128),
                     0, stream, An, Bn, labels, pN, pD, out);
  hipLaunchKernelGGL(loss_kernel, dim3(BATCH / 256), dim3(256), 0, stream,
                     pN, pD, out);
}